// Round 7
// baseline (1009.487 us; speedup 1.0000x reference)
//
#include <hip/hip_runtime.h>
#include <hip/hip_bf16.h>
#include <stdint.h>

#define N_BANK 131072
#define B_ROWS 256
#define DIM 2048
#define HID 512
#define CAND_CAP 1024
#define WIN 64
#define Z_THRESH 2.5528f

typedef __attribute__((ext_vector_type(8))) short bf16x8;
typedef __attribute__((ext_vector_type(8))) unsigned short ushort8;
typedef __attribute__((ext_vector_type(4))) float f32x4;

// ---------------- threefry2x32 (exact JAX semantics; verified R1-R6) ----------------
__device__ __forceinline__ void threefry2x32(uint32_t k0, uint32_t k1,
                                             uint32_t x0, uint32_t x1,
                                             uint32_t& o0, uint32_t& o1) {
  uint32_t ks0 = k0, ks1 = k1, ks2 = k0 ^ k1 ^ 0x1BD11BDAu;
  uint32_t ks[3] = {ks0, ks1, ks2};
  x0 += ks0; x1 += ks1;
  const int rotA[4] = {13, 15, 26, 6};
  const int rotB[4] = {17, 29, 16, 24};
  #pragma unroll
  for (int g = 0; g < 5; ++g) {
    const int* rr = (g & 1) ? rotB : rotA;
    #pragma unroll
    for (int i = 0; i < 4; ++i) {
      x0 += x1;
      x1 = (x1 << rr[i]) | (x1 >> (32 - rr[i]));
      x1 ^= x0;
    }
    x0 += ks[(g + 1) % 3];
    x1 += ks[(g + 2) % 3] + (uint32_t)(g + 1);
  }
  o0 = x0; o1 = x1;
}

__device__ __forceinline__ void jax_split(uint32_t k0, uint32_t k1,
                                          uint32_t& a0, uint32_t& a1,
                                          uint32_t& b0, uint32_t& b1) {
  uint32_t o00, o10, o01, o11;
  threefry2x32(k0, k1, 0u, 2u, o00, o10);
  threefry2x32(k0, k1, 1u, 3u, o01, o11);
  a0 = o00; a1 = o01;
  b0 = o10; b1 = o11;
}

__device__ __forceinline__ ushort f2bf(float f) {
  uint32_t u = __float_as_uint(f);
  return (ushort)((u + 0x7FFFu + ((u >> 16) & 1u)) >> 16);  // RNE
}

// hw packed f32->bf16 (rounding mode need not match f2bf: bf16 sims only gate
// the candidate window; final picks come from the fp64 rerank)
__device__ __forceinline__ uint32_t cvt_pk(float lo, float hi) {
  uint32_t d;
  asm("v_cvt_pk_bf16_f32 %0, %1, %2" : "=v"(d) : "v"(lo), "v"(hi));
  return d;
}

__device__ __forceinline__ bf16x8 cvt8(float4 a, float4 b) {
  union { uint32_t u[4]; bf16x8 v; } r;
  r.u[0] = cvt_pk(a.x, a.y);
  r.u[1] = cvt_pk(a.z, a.w);
  r.u[2] = cvt_pk(b.x, b.y);
  r.u[3] = cvt_pk(b.z, b.w);
  return r.v;
}

// ---------------- prep: norm + thr + A->bf16 in MFMA-fragment order ----------------
// Abf 16B-chunk layout: chunk = ks*1024 + fi*64 + lane, where the chunk holds
// row r = fi*16 + (lane&15), k = ks*32 + (lane>>4)*8 .. +8.  A wave's frag
// load for (ks, fi) is 64 consecutive chunks = 1KB contiguous.
__global__ __launch_bounds__(256) void prep_kernel(const float* __restrict__ inputs,
                                                   ushort* __restrict__ Abf,
                                                   float* __restrict__ invn,
                                                   float* __restrict__ thr,
                                                   int* __restrict__ cand_cnt,
                                                   unsigned long long* __restrict__ pos_comb) {
  int r = blockIdx.x, t = threadIdx.x;
  const float* src = inputs + (size_t)r * DIM + t * 8;
  float4 v0 = *(const float4*)(src);
  float4 v1 = *(const float4*)(src + 4);
  double s = (double)v0.x * v0.x + (double)v0.y * v0.y + (double)v0.z * v0.z + (double)v0.w * v0.w
           + (double)v1.x * v1.x + (double)v1.y * v1.y + (double)v1.z * v1.z + (double)v1.w * v1.w;
  ushort8 c = { f2bf(v0.x), f2bf(v0.y), f2bf(v0.z), f2bf(v0.w),
                f2bf(v1.x), f2bf(v1.y), f2bf(v1.z), f2bf(v1.w) };
  int ks = t >> 2;                 // k-slice of 32
  int lk = t & 3;                  // 8-elem chunk within slice
  int fi = r >> 4;                 // 16-row tile
  int lane = lk * 16 + (r & 15);
  int chunk = ks * 1024 + fi * 64 + lane;
  *(ushort8*)(Abf + (size_t)chunk * 8) = c;
  __shared__ double red[256];
  red[t] = s;
  __syncthreads();
  for (int st = 128; st; st >>= 1) {
    if (t < st) red[t] += red[t + st];
    __syncthreads();
  }
  if (t == 0) {
    float nrm = sqrtf((float)red[0]);
    invn[r] = 1.0f / nrm;
    thr[r] = Z_THRESH * nrm;
    cand_cnt[r] = 0;
    pos_comb[r] = 0ull;
  }
}

// ---------------- positive pick: class-bitmap + N-parallel scan (verified R6) ----------------
__global__ __launch_bounds__(256) void pos_scan(const int* __restrict__ labels,
                                                const int* __restrict__ targets,
                                                unsigned long long* __restrict__ pos_comb) {
  __shared__ int targ_s[256];
  __shared__ uint32_t bm[128];   // 4096 classes
  int tid = threadIdx.x;
  if (tid < 128) bm[tid] = 0u;
  int tg = targets[tid];
  targ_s[tid] = tg;
  __syncthreads();
  atomicOr(&bm[tg >> 5], 1u << (tg & 31));
  __syncthreads();
  int n = blockIdx.x * 256 + tid;
  int c = labels[n];
  if ((bm[c >> 5] >> (c & 31)) & 1u) {
    uint32_t kn0, kn1, kp0, kp1;
    jax_split(0u, 42u, kn0, kn1, kp0, kp1);
    for (int r = 0; r < 256; ++r) {
      if (targ_s[r] == c) {
        uint32_t i = (uint32_t)r * (uint32_t)N_BANK + (uint32_t)n;
        uint32_t o0, o1, bits;
        if (i < (1u << 24)) { threefry2x32(kp0, kp1, i, i + (1u << 24), o0, o1); bits = o0; }
        else                { threefry2x32(kp0, kp1, i - (1u << 24), i, o0, o1); bits = o1; }
        unsigned long long comb =
            ((unsigned long long)((bits >> 9) + 1u) << 32) | (unsigned long long)(131071u - (uint32_t)n);
        atomicMax(&pos_comb[r], comb);
      }
    }
  }
}

// ---------------- bf16 MFMA GEMM + fused select: NO LDS, NO BARRIERS ----------------
// Each wave: full M=256 x 32 N-cols (F read exactly once, wave-exclusive).
// Per iter (K=32): 16 A-frag loads (L2, fragment-order Abf), 4 F loads (HBM,
// ping-pong reg sets, issued AFTER A so the MFMA's A-wait leaves them in
// flight for a full iteration >= HBM latency), 8 cvt_pk, 32 MFMA.  Waves
// never sync -> stalls overlap freely across the 2 waves/SIMD.
#define KSTEP(KS, FC, FN, PREF)                                               \
  {                                                                           \
    const ushort* ac = abase + (size_t)(KS) * 8192;                           \
    bf16x8 af[16];                                                            \
    _Pragma("unroll")                                                         \
    for (int fi = 0; fi < 16; ++fi)                                           \
      af[fi] = *(const bf16x8*)(ac + fi * 512);                               \
    if (PREF) {                                                               \
      const float* p0 = f0 + ((KS) + 1) * 32;                                 \
      const float* p1 = f1 + ((KS) + 1) * 32;                                 \
      FN[0] = *(const float4*)(p0);                                           \
      FN[1] = *(const float4*)(p0 + 4);                                       \
      FN[2] = *(const float4*)(p1);                                           \
      FN[3] = *(const float4*)(p1 + 4);                                       \
    }                                                                         \
    bf16x8 b0 = cvt8(FC[0], FC[1]);                                           \
    bf16x8 b1 = cvt8(FC[2], FC[3]);                                           \
    _Pragma("unroll")                                                         \
    for (int fi = 0; fi < 16; ++fi) {                                         \
      acc[fi][0] = __builtin_amdgcn_mfma_f32_16x16x32_bf16(af[fi], b0,        \
                                                           acc[fi][0], 0, 0, 0); \
      acc[fi][1] = __builtin_amdgcn_mfma_f32_16x16x32_bf16(af[fi], b1,        \
                                                           acc[fi][1], 0, 0, 0); \
    }                                                                         \
  }

__global__ __launch_bounds__(256, 2) void gemm_select(
    const ushort* __restrict__ Abf, const float* __restrict__ F,
    const float* __restrict__ thr, const int* __restrict__ labels,
    const int* __restrict__ targets, float* __restrict__ cand_val,
    int* __restrict__ cand_idx, int* __restrict__ cand_cnt) {
  const int tid = threadIdx.x;
  const int lane = tid & 63;
  const int wid = tid >> 6;
  const int lr = lane & 15;
  const int lk = lane >> 4;
  const int col0 = blockIdx.x * 128 + wid * 32;          // wave's 32 cols
  const float* f0 = F + (size_t)(col0 + lr) * DIM + lk * 8;       // fj=0
  const float* f1 = F + (size_t)(col0 + 16 + lr) * DIM + lk * 8;  // fj=1
  const ushort* abase = Abf + (size_t)lane * 8;

  f32x4 acc[16][2];
  #pragma unroll
  for (int i = 0; i < 16; ++i) {
    acc[i][0] = (f32x4){0.f, 0.f, 0.f, 0.f};
    acc[i][1] = (f32x4){0.f, 0.f, 0.f, 0.f};
  }

  float4 fE[4], fO[4];
  // prologue: F(0) -> fE
  fE[0] = *(const float4*)(f0);
  fE[1] = *(const float4*)(f0 + 4);
  fE[2] = *(const float4*)(f1);
  fE[3] = *(const float4*)(f1 + 4);

  for (int k2 = 0; k2 < 31; ++k2) {
    KSTEP(2 * k2, fE, fO, 1);
    KSTEP(2 * k2 + 1, fO, fE, 1);
  }
  KSTEP(62, fE, fO, 1);
  KSTEP(63, fO, fE, 0);

  // fused threshold selection (S never hits memory)
  int lb[2];
  lb[0] = labels[col0 + lr];
  lb[1] = labels[col0 + 16 + lr];
  #pragma unroll
  for (int fi = 0; fi < 16; ++fi) {
    #pragma unroll
    for (int reg = 0; reg < 4; ++reg) {
      int row = fi * 16 + lk * 4 + reg;   // C/D: col=lane&15, row=(lane>>4)*4+reg
      float tr = thr[row];
      int tg = targets[row];
      #pragma unroll
      for (int fj = 0; fj < 2; ++fj) {
        float v = acc[fi][fj][reg];
        if (v > tr && lb[fj] != tg) {
          int p = atomicAdd(&cand_cnt[row], 1);
          if (p < CAND_CAP) {
            cand_val[row * CAND_CAP + p] = v;
            cand_idx[row * CAND_CAP + p] = col0 + fj * 16 + lr;
          }
        }
      }
    }
  }
}

// ---------------- windowed exact fp64 re-rank (+ inline neg_pick; verified R3-R6) ----------------
__global__ __launch_bounds__(512) void rerank(const float* __restrict__ inputs,
                                              const float* __restrict__ F,
                                              const float* __restrict__ cand_val,
                                              const int* __restrict__ cand_idx,
                                              const int* __restrict__ cand_cnt,
                                              int* __restrict__ neg_sel) {
  int r = blockIdx.x;
  int tid = threadIdx.x;
  int m = cand_cnt[r]; if (m > CAND_CAP) m = CAND_CAP;
  __shared__ float vals[CAND_CAP];
  __shared__ int idxs[CAND_CAP];
  __shared__ float xr[DIM];
  __shared__ int wlist[WIN];
  __shared__ double dvals[WIN];
  __shared__ int wcnt, s_pick;
  if (tid == 0) {
    wcnt = 0; neg_sel[r] = 0;
    uint32_t kn0, kn1, kp0, kp1, k10, k11, k20, k21, o0, o1, hi, lo;
    jax_split(0u, 42u, kn0, kn1, kp0, kp1);
    jax_split(kn0, kn1, k10, k11, k20, k21);
    if (r < 128) { threefry2x32(k10, k11, (uint32_t)r, (uint32_t)(r + 128), o0, o1); hi = o0; }
    else         { threefry2x32(k10, k11, (uint32_t)(r - 128), (uint32_t)r, o0, o1); hi = o1; }
    if (r < 128) { threefry2x32(k20, k21, (uint32_t)r, (uint32_t)(r + 128), o0, o1); lo = o0; }
    else         { threefry2x32(k20, k21, (uint32_t)(r - 128), (uint32_t)r, o0, o1); lo = o1; }
    s_pick = (int)(((hi % 500u) * 296u + (lo % 500u)) % 500u);
  }
  for (int d = tid; d < DIM; d += 512) xr[d] = inputs[(size_t)r * DIM + d];
  for (int c = tid; c < m; c += 512) {
    vals[c] = cand_val[r * CAND_CAP + c];
    idxs[c] = cand_idx[r * CAND_CAP + c];
  }
  __syncthreads();
  int pick = s_pick;
  int lo = pick - 32; if (lo < 0) lo = 0;
  int hi = pick + 32; if (hi > m) hi = m;
  for (int c = tid; c < m; c += 512) {
    float v = vals[c]; int id = idxs[c]; int rk = 0;
    for (int j = 0; j < m; ++j) {
      float vj = vals[j];
      rk += (vj > v) || (vj == v && idxs[j] < id);
    }
    if (rk >= lo && rk < hi) { int p = atomicAdd(&wcnt, 1); if (p < WIN) wlist[p] = c; }
  }
  __syncthreads();
  int wn = wcnt; if (wn > WIN) wn = WIN;
  int wave = tid >> 6, lane = tid & 63;
  for (int w = wave; w < wn; w += 8) {
    const float* f = F + (size_t)idxs[wlist[w]] * DIM;
    double s = 0.0;
    for (int d = lane; d < DIM; d += 64) s += (double)xr[d] * (double)f[d];
    for (int off = 32; off; off >>= 1) s += __shfl_down(s, off);
    if (lane == 0) dvals[w] = s;
  }
  __syncthreads();
  if (tid < wn) {
    double v = dvals[tid]; int id = idxs[wlist[tid]]; int rk = lo;
    for (int j = 0; j < wn; ++j) {
      double vj = dvals[j];
      rk += (vj > v) || (vj == v && idxs[wlist[j]] < id);
    }
    if (rk == pick) neg_sel[r] = id;
  }
}

// ---------------- siamese head: one block does pos+neg (verified R3-R6) ----------------
__global__ __launch_bounds__(256) void head_kernel(const float* __restrict__ inputs,
                                                   const float* __restrict__ F,
                                                   const float* __restrict__ invn,
                                                   const unsigned long long* __restrict__ pos_comb,
                                                   const int* __restrict__ neg_sel,
                                                   const float* __restrict__ W1,
                                                   const float* __restrict__ b1,
                                                   const float* __restrict__ W2,
                                                   const float* __restrict__ b2,
                                                   float* __restrict__ terms) {
  int r = blockIdx.x;
  unsigned long long pc = pos_comb[r];
  int sp = pc ? (int)(131071u - (uint32_t)(pc & 0xffffffffull)) : 0;
  int sn = neg_sel[r];
  __shared__ float zp[DIM];
  __shared__ float zn[DIM];
  __shared__ float2 red[256];
  float inv = invn[r];
  const float* xr = inputs + (size_t)r * DIM;
  const float* fp = F + (size_t)sp * DIM;
  const float* fn = F + (size_t)sn * DIM;
  for (int d = threadIdx.x; d < DIM; d += 256) {
    float x = xr[d] * inv;
    zp[d] = fabsf(x - fp[d]);
    zn[d] = fabsf(x - fn[d]);
  }
  __syncthreads();
  int j = threadIdx.x;
  float ap0 = 0.f, ap1 = 0.f, an0 = 0.f, an1 = 0.f;
  for (int d = 0; d < DIM; ++d) {
    float w0 = W1[(size_t)d * HID + j];
    float w1 = W1[(size_t)d * HID + j + 256];
    float zpd = zp[d], znd = zn[d];
    ap0 = fmaf(zpd, w0, ap0); ap1 = fmaf(zpd, w1, ap1);
    an0 = fmaf(znd, w0, an0); an1 = fmaf(znd, w1, an1);
  }
  float bj0 = b1[j], bj1 = b1[j + 256];
  float w20 = W2[j], w21 = W2[j + 256];
  ap0 += bj0; ap1 += bj1; an0 += bj0; an1 += bj1;
  float hp0 = ap0 >= 0.f ? ap0 : 0.01f * ap0;
  float hp1 = ap1 >= 0.f ? ap1 : 0.01f * ap1;
  float hn0 = an0 >= 0.f ? an0 : 0.01f * an0;
  float hn1 = an1 >= 0.f ? an1 : 0.01f * an1;
  red[j] = make_float2(hp0 * w20 + hp1 * w21, hn0 * w20 + hn1 * w21);
  __syncthreads();
  for (int st = 128; st; st >>= 1) {
    if (j < st) {
      red[j].x += red[j + st].x;
      red[j].y += red[j + st].y;
    }
    __syncthreads();
  }
  if (j == 0) {
    float lp = red[0].x + b2[0];
    float ln = red[0].y + b2[0];
    float xp = -lp;
    float sp_t = fmaxf(xp, 0.f) + log1pf(expf(-fabsf(xp)));
    float sn_t = fmaxf(ln, 0.f) + log1pf(expf(-fabsf(ln)));
    terms[2 * r] = sp_t * (1.0f / 256.0f);
    terms[2 * r + 1] = sn_t * (1.0f / 256.0f);
  }
}

__global__ __launch_bounds__(512) void final_reduce(const float* __restrict__ terms,
                                                    float* __restrict__ out) {
  __shared__ float red[512];
  int t = threadIdx.x;
  red[t] = terms[t];
  __syncthreads();
  for (int st = 256; st; st >>= 1) {
    if (t < st) red[t] += red[t + st];
    __syncthreads();
  }
  if (t == 0) out[0] = red[0];
}

// ---------------- launch ----------------
extern "C" void kernel_launch(void* const* d_in, const int* in_sizes, int n_in,
                              void* d_out, int out_size, void* d_ws, size_t ws_size,
                              hipStream_t stream) {
  (void)in_sizes; (void)n_in; (void)out_size; (void)ws_size;
  const float* inputs = (const float*)d_in[0];
  const int* targets  = (const int*)d_in[1];
  const float* F      = (const float*)d_in[2];
  const int* labels   = (const int*)d_in[3];
  const float* W1     = (const float*)d_in[4];
  const float* b1     = (const float*)d_in[5];
  const float* W2     = (const float*)d_in[6];
  const float* b2     = (const float*)d_in[7];
  float* out = (float*)d_out;

  char* ws = (char*)d_ws;
  size_t off = 0;
  ushort* Abf     = (ushort*)(ws + off); off += (size_t)B_ROWS * DIM * 2;        // 1 MB
  float* cand_val = (float*)(ws + off); off += (size_t)B_ROWS * CAND_CAP * 4;    // 1 MB
  int* cand_idx   = (int*)(ws + off);   off += (size_t)B_ROWS * CAND_CAP * 4;    // 1 MB
  int* cand_cnt   = (int*)(ws + off);   off += 1024;
  unsigned long long* pos_comb = (unsigned long long*)(ws + off); off += 2048;
  int* neg_sel    = (int*)(ws + off);   off += 1024;
  float* invn     = (float*)(ws + off); off += 1024;
  float* thr      = (float*)(ws + off); off += 1024;
  float* terms    = (float*)(ws + off); off += 2048;

  prep_kernel<<<B_ROWS, 256, 0, stream>>>(inputs, Abf, invn, thr, cand_cnt, pos_comb);
  pos_scan<<<N_BANK / 256, 256, 0, stream>>>(labels, targets, pos_comb);
  gemm_select<<<N_BANK / 128, 256, 0, stream>>>(Abf, F, thr, labels, targets,
                                                cand_val, cand_idx, cand_cnt);
  rerank<<<B_ROWS, 512, 0, stream>>>(inputs, F, cand_val, cand_idx, cand_cnt, neg_sel);
  head_kernel<<<B_ROWS, 256, 0, stream>>>(inputs, F, invn, pos_comb, neg_sel,
                                          W1, b1, W2, b2, terms);
  final_reduce<<<1, 512, 0, stream>>>(terms, out);
}

// Round 9
// 688.786 us; speedup vs baseline: 1.4656x; 1.4656x over previous
//
#include <hip/hip_runtime.h>
#include <hip/hip_bf16.h>
#include <stdint.h>

#define N_BANK 131072
#define B_ROWS 256
#define DIM 2048
#define HID 512
#define CAND_CAP 1024
#define WIN 64
#define Z_THRESH 2.5528f

typedef __attribute__((ext_vector_type(8))) short bf16x8;
typedef __attribute__((ext_vector_type(8))) unsigned short ushort8;
typedef __attribute__((ext_vector_type(4))) float f32x4;

// ---------------- threefry2x32 (exact JAX semantics; verified R1-R7) ----------------
__device__ __forceinline__ void threefry2x32(uint32_t k0, uint32_t k1,
                                             uint32_t x0, uint32_t x1,
                                             uint32_t& o0, uint32_t& o1) {
  uint32_t ks0 = k0, ks1 = k1, ks2 = k0 ^ k1 ^ 0x1BD11BDAu;
  uint32_t ks[3] = {ks0, ks1, ks2};
  x0 += ks0; x1 += ks1;
  const int rotA[4] = {13, 15, 26, 6};
  const int rotB[4] = {17, 29, 16, 24};
  #pragma unroll
  for (int g = 0; g < 5; ++g) {
    const int* rr = (g & 1) ? rotB : rotA;
    #pragma unroll
    for (int i = 0; i < 4; ++i) {
      x0 += x1;
      x1 = (x1 << rr[i]) | (x1 >> (32 - rr[i]));
      x1 ^= x0;
    }
    x0 += ks[(g + 1) % 3];
    x1 += ks[(g + 2) % 3] + (uint32_t)(g + 1);
  }
  o0 = x0; o1 = x1;
}

__device__ __forceinline__ void jax_split(uint32_t k0, uint32_t k1,
                                          uint32_t& a0, uint32_t& a1,
                                          uint32_t& b0, uint32_t& b1) {
  uint32_t o00, o10, o01, o11;
  threefry2x32(k0, k1, 0u, 2u, o00, o10);
  threefry2x32(k0, k1, 1u, 3u, o01, o11);
  a0 = o00; a1 = o01;
  b0 = o10; b1 = o11;
}

__device__ __forceinline__ ushort f2bf(float f) {
  uint32_t u = __float_as_uint(f);
  return (ushort)((u + 0x7FFFu + ((u >> 16) & 1u)) >> 16);  // RNE
}

__device__ __forceinline__ uint32_t cvt_pk(float lo, float hi) {
  uint32_t d;
  asm("v_cvt_pk_bf16_f32 %0, %1, %2" : "=v"(d) : "v"(lo), "v"(hi));
  return d;
}

__device__ __forceinline__ bf16x8 cvt8(float4 a, float4 b) {
  union { uint32_t u[4]; bf16x8 v; } r;
  r.u[0] = cvt_pk(a.x, a.y);
  r.u[1] = cvt_pk(a.z, a.w);
  r.u[2] = cvt_pk(b.x, b.y);
  r.u[3] = cvt_pk(b.z, b.w);
  return r.v;
}

__device__ __forceinline__ void async16(const void* g, void* l) {
  __builtin_amdgcn_global_load_lds((const __attribute__((address_space(1))) void*)g,
                                   (__attribute__((address_space(3))) void*)l, 16, 0, 0);
}

// ---------------- zero the atomics (replaces hipMemsetAsync) ----------------
__global__ void zero_kernel(int* __restrict__ cand_cnt,
                            unsigned long long* __restrict__ pos_comb) {
  int t = threadIdx.x;
  cand_cnt[t] = 0;
  pos_comb[t] = 0ull;
}

// ---------------- fused prep (rows 0-255) + pos_scan (all 512 blocks) ----------------
// Abf fragment-order layout (verified R5/R6): 16B chunk =
// kt*2048 + wid*512 + kk*256 + fi*64 + lk*16 + lr, holding row=wid*64+fi*16+lr,
// k = kt*64 + kk*32 + lk*8 .. +8.
__global__ __launch_bounds__(256) void prep_pos(const float* __restrict__ inputs,
                                                ushort* __restrict__ Abf,
                                                float* __restrict__ invn,
                                                float* __restrict__ thr,
                                                const int* __restrict__ labels,
                                                const int* __restrict__ targets,
                                                unsigned long long* __restrict__ pos_comb) {
  int bid = blockIdx.x, t = threadIdx.x;
  __shared__ int targ_s[256];
  __shared__ uint32_t bm[128];
  __shared__ double red[256];
  if (t < 128) bm[t] = 0u;
  int tg = targets[t];
  targ_s[t] = tg;

  double s = 0.0;
  if (bid < 256) {
    const float* src = inputs + (size_t)bid * DIM + t * 8;
    float4 v0 = *(const float4*)(src);
    float4 v1 = *(const float4*)(src + 4);
    s = (double)v0.x * v0.x + (double)v0.y * v0.y + (double)v0.z * v0.z + (double)v0.w * v0.w
      + (double)v1.x * v1.x + (double)v1.y * v1.y + (double)v1.z * v1.z + (double)v1.w * v1.w;
    ushort8 c = { f2bf(v0.x), f2bf(v0.y), f2bf(v0.z), f2bf(v0.w),
                  f2bf(v1.x), f2bf(v1.y), f2bf(v1.z), f2bf(v1.w) };
    int kt = t >> 3;
    int kk = (t >> 2) & 1;
    int lk = t & 3;
    int chunk = kt * 2048 + (bid >> 6) * 512 + kk * 256 + ((bid >> 4) & 3) * 64
              + lk * 16 + (bid & 15);
    *(ushort8*)(Abf + (size_t)chunk * 8) = c;
  }
  __syncthreads();
  atomicOr(&bm[tg >> 5], 1u << (tg & 31));
  __syncthreads();

  int n = bid * 256 + t;
  int c = labels[n];
  if ((bm[c >> 5] >> (c & 31)) & 1u) {
    uint32_t kn0, kn1, kp0, kp1;
    jax_split(0u, 42u, kn0, kn1, kp0, kp1);
    for (int r = 0; r < 256; ++r) {
      if (targ_s[r] == c) {
        uint32_t i = (uint32_t)r * (uint32_t)N_BANK + (uint32_t)n;
        uint32_t o0, o1, bits;
        if (i < (1u << 24)) { threefry2x32(kp0, kp1, i, i + (1u << 24), o0, o1); bits = o0; }
        else                { threefry2x32(kp0, kp1, i - (1u << 24), i, o0, o1); bits = o1; }
        unsigned long long comb =
            ((unsigned long long)((bits >> 9) + 1u) << 32) | (unsigned long long)(131071u - (uint32_t)n);
        atomicMax(&pos_comb[r], comb);
      }
    }
  }

  if (bid < 256) {
    red[t] = s;
    __syncthreads();
    for (int st = 128; st; st >>= 1) {
      if (t < st) red[t] += red[t + st];
      __syncthreads();
    }
    if (t == 0) {
      float nrm = sqrtf((float)red[0]);
      invn[bid] = 1.0f / nrm;
      thr[bid] = Z_THRESH * nrm;
    }
  }
}

// ---------------- bf16 MFMA GEMM + fused select: counted-vmcnt pipeline ----------------
// 32 K-tiles of 64 (kt = 0..31 EXACTLY -- R8's crash was a 64-step loop here).
// A: fragment-order reg loads (L2), double set. F: fp32 global_load_lds into
// QUAD-buffered 64KB LDS (depth-3 stage); bf16 cvt at read. Per step:
// LOADA(kt+1) | STAGE(kt+3) | MFMA(kt) | s_waitcnt vmcnt(16)+s_barrier.
// FIFO: compiler's A-wait (vmcnt(16)) at step kt drains F(kt+1) (older) ->
// every F tile has ~2 K-steps in flight; vmcnt never drains to 0 in-loop.
// LDS XOR swizzle (Rule 21): phys16B = log ^ (row&15), inverse on global src.
#define STAGE(KTF, BUF)                                                       \
  {                                                                           \
    _Pragma("unroll")                                                         \
    for (int q = 0; q < 4; ++q) {                                             \
      int jj = wid * 4 + q;                                                   \
      int row_local = jj * 4 + (lane >> 4);                                   \
      int logc = (lane & 15) ^ (row_local & 15);                              \
      const float* g = F + (size_t)(bn + row_local) * DIM + (KTF) * 64 + logc * 4; \
      async16(g, (char*)(BUF) + jj * 1024);                                   \
    }                                                                         \
  }

#define LOADA(KT, DST)                                                        \
  {                                                                           \
    const ushort* ab = aptr + (size_t)(KT) * 16384;                           \
    _Pragma("unroll")                                                         \
    for (int q = 0; q < 8; ++q) DST[q] = *(const bf16x8*)(ab + q * 512);      \
  }

#define GMFMA(PR, AC)                                                         \
  {                                                                           \
    const float4* bp4 = (const float4*)(PR);                                  \
    _Pragma("unroll")                                                         \
    for (int kk = 0; kk < 2; ++kk) {                                          \
      bf16x8 bfv[4];                                                          \
      _Pragma("unroll")                                                       \
      for (int fj = 0; fj < 4; ++fj) {                                        \
        float4 x0 = bp4[(fj * 16 + lr) * 16 + ((kk * 8 + lk * 2) ^ lr)];      \
        float4 x1 = bp4[(fj * 16 + lr) * 16 + ((kk * 8 + lk * 2 + 1) ^ lr)];  \
        bfv[fj] = cvt8(x0, x1);                                               \
      }                                                                       \
      _Pragma("unroll")                                                       \
      for (int fi = 0; fi < 4; ++fi)                                          \
        _Pragma("unroll")                                                     \
        for (int fj = 0; fj < 4; ++fj)                                        \
          acc[fi][fj] = __builtin_amdgcn_mfma_f32_16x16x32_bf16(              \
              AC[kk * 4 + fi], bfv[fj], acc[fi][fj], 0, 0, 0);                \
    }                                                                         \
  }

#define SB() __builtin_amdgcn_sched_barrier(0)
#define WAITBAR(N) asm volatile("s_waitcnt vmcnt(" #N ")\n\ts_barrier" ::: "memory")
#define ROT4() { float* tt = p0; p0 = p1; p1 = p2; p2 = p3; p3 = tt; }

__global__ __launch_bounds__(256, 2) void gemm_select(
    const ushort* __restrict__ Abf, const float* __restrict__ F,
    const float* __restrict__ thr, const int* __restrict__ labels,
    const int* __restrict__ targets, float* __restrict__ cand_val,
    int* __restrict__ cand_idx, int* __restrict__ cand_cnt) {
  __shared__ __align__(16) float Bs32[4][64 * 64];   // 64KB fp32 F tiles
  const int tid = threadIdx.x;
  const int bn = blockIdx.x * 64;
  const int wid = tid >> 6;
  const int lane = tid & 63;
  const int lr = lane & 15;
  const int lk = lane >> 4;
  const ushort* aptr = Abf + (size_t)(wid * 512 + lane) * 8;

  f32x4 acc[4][4];
  #pragma unroll
  for (int i = 0; i < 4; ++i)
    #pragma unroll
    for (int j = 0; j < 4; ++j) acc[i][j] = (f32x4){0.f, 0.f, 0.f, 0.f};

  bf16x8 A0[8], A1[8];
  float* p0 = &Bs32[0][0];
  float* p1 = &Bs32[1][0];
  float* p2 = &Bs32[2][0];
  float* p3 = &Bs32[3][0];

  // prologue: F0,F1,F2 staged; A0 regs; drain F0 (leave A0(8)+F1(4)+F2(4)=16)
  STAGE(0, p0);
  SB();
  LOADA(0, A0);
  SB();
  STAGE(1, p1);
  SB();
  STAGE(2, p2);
  WAITBAR(16);

  #pragma unroll 1
  for (int k2 = 0; k2 < 14; ++k2) {   // kt = 0..27
    int kt = 2 * k2;
    LOADA(kt + 1, A1);
    SB();
    STAGE(kt + 3, p3);
    SB();
    GMFMA(p0, A0);
    WAITBAR(16);
    ROT4();
    LOADA(kt + 2, A0);
    SB();
    STAGE(kt + 4, p3);
    SB();
    GMFMA(p0, A1);
    WAITBAR(16);
    ROT4();
  }
  // kt = 28: last stage (F31)
  LOADA(29, A1);
  SB();
  STAGE(31, p3);
  SB();
  GMFMA(p0, A0);
  WAITBAR(16);
  ROT4();
  // kt = 29
  LOADA(30, A0);
  SB();
  GMFMA(p0, A1);
  WAITBAR(12);
  ROT4();
  // kt = 30
  LOADA(31, A1);
  SB();
  GMFMA(p0, A0);
  WAITBAR(8);
  ROT4();
  // kt = 31
  GMFMA(p0, A1);

  // fused threshold selection (S never hits memory)
  int lb[4];
  #pragma unroll
  for (int fj = 0; fj < 4; ++fj) lb[fj] = labels[bn + fj * 16 + lr];
  #pragma unroll
  for (int fi = 0; fi < 4; ++fi) {
    #pragma unroll
    for (int reg = 0; reg < 4; ++reg) {
      int row = wid * 64 + fi * 16 + lk * 4 + reg;  // C/D: col=lane&15, row=(lane>>4)*4+reg
      float tr = thr[row];
      int tg = targets[row];
      #pragma unroll
      for (int fj = 0; fj < 4; ++fj) {
        float v = acc[fi][fj][reg];
        if (v > tr && lb[fj] != tg) {
          int p = atomicAdd(&cand_cnt[row], 1);
          if (p < CAND_CAP) {
            cand_val[row * CAND_CAP + p] = v;
            cand_idx[row * CAND_CAP + p] = bn + fj * 16 + lr;
          }
        }
      }
    }
  }
}

// ---------------- tail: windowed fp64 rerank + Z-matrix write ----------------
__global__ __launch_bounds__(512) void tail_kernel(const float* __restrict__ inputs,
                                                   const float* __restrict__ F,
                                                   const float* __restrict__ cand_val,
                                                   const int* __restrict__ cand_idx,
                                                   const int* __restrict__ cand_cnt,
                                                   const unsigned long long* __restrict__ pos_comb,
                                                   const float* __restrict__ invn,
                                                   float* __restrict__ Z) {
  int r = blockIdx.x;
  int tid = threadIdx.x;
  int m = cand_cnt[r]; if (m > CAND_CAP) m = CAND_CAP;
  __shared__ float vals[CAND_CAP];
  __shared__ int idxs[CAND_CAP];
  __shared__ float xr[DIM];
  __shared__ int wlist[WIN];
  __shared__ double dvals[WIN];
  __shared__ int wcnt, s_pick, s_neg;

  if (tid == 0) {
    wcnt = 0; s_neg = 0;
    uint32_t kn0, kn1, kp0, kp1, k10, k11, k20, k21, o0, o1, hi, lo;
    jax_split(0u, 42u, kn0, kn1, kp0, kp1);
    jax_split(kn0, kn1, k10, k11, k20, k21);
    if (r < 128) { threefry2x32(k10, k11, (uint32_t)r, (uint32_t)(r + 128), o0, o1); hi = o0; }
    else         { threefry2x32(k10, k11, (uint32_t)(r - 128), (uint32_t)r, o0, o1); hi = o1; }
    if (r < 128) { threefry2x32(k20, k21, (uint32_t)r, (uint32_t)(r + 128), o0, o1); lo = o0; }
    else         { threefry2x32(k20, k21, (uint32_t)(r - 128), (uint32_t)r, o0, o1); lo = o1; }
    s_pick = (int)(((hi % 500u) * 296u + (lo % 500u)) % 500u);
  }
  for (int d = tid; d < DIM; d += 512) xr[d] = inputs[(size_t)r * DIM + d];
  for (int c = tid; c < m; c += 512) {
    vals[c] = cand_val[r * CAND_CAP + c];
    idxs[c] = cand_idx[r * CAND_CAP + c];
  }
  __syncthreads();
  int pick = s_pick;
  int lo = pick - 32; if (lo < 0) lo = 0;
  int hi = pick + 32; if (hi > m) hi = m;
  for (int c = tid; c < m; c += 512) {
    float v = vals[c]; int id = idxs[c]; int rk = 0;
    for (int j = 0; j < m; ++j) {
      float vj = vals[j];
      rk += (vj > v) || (vj == v && idxs[j] < id);
    }
    if (rk >= lo && rk < hi) { int p = atomicAdd(&wcnt, 1); if (p < WIN) wlist[p] = c; }
  }
  __syncthreads();
  int wn = wcnt; if (wn > WIN) wn = WIN;
  int wave = tid >> 6, lane = tid & 63;
  for (int w = wave; w < wn; w += 8) {
    const float* f = F + (size_t)idxs[wlist[w]] * DIM;
    double s = 0.0;
    for (int d = lane; d < DIM; d += 64) s += (double)xr[d] * (double)f[d];
    for (int off = 32; off; off >>= 1) s += __shfl_down(s, off);
    if (lane == 0) dvals[w] = s;
  }
  __syncthreads();
  if (tid < wn) {
    double v = dvals[tid]; int id = idxs[wlist[tid]]; int rk = lo;
    for (int j = 0; j < wn; ++j) {
      double vj = dvals[j];
      rk += (vj > v) || (vj == v && idxs[wlist[j]] < id);
    }
    if (rk == pick) s_neg = id;
  }
  __syncthreads();

  unsigned long long pc = pos_comb[r];
  int sp = pc ? (int)(131071u - (uint32_t)(pc & 0xffffffffull)) : 0;
  int sn = s_neg;
  float inv = invn[r];
  const float* fp = F + (size_t)sp * DIM;
  const float* fn = F + (size_t)sn * DIM;
  float* zp = Z + (size_t)(2 * r) * DIM;
  float* zn = Z + (size_t)(2 * r + 1) * DIM;
  for (int d = tid; d < DIM; d += 512) {
    float x = xr[d] * inv;
    zp[d] = fabsf(x - fp[d]);
    zn[d] = fabsf(x - fn[d]);
  }
}

// ---------------- head GEMM: H = Z @ W1, fused leaky+W2 partial reduce ----------------
// W1 read exactly ONCE (vs 4MB x 256 blocks before). Per-thread K order is
// sequential d=0..2047 -> H bitwise identical to the previous per-row head.
__global__ __launch_bounds__(256) void head_gemm(const float* __restrict__ Z,
                                                 const float* __restrict__ W1,
                                                 const float* __restrict__ b1,
                                                 const float* __restrict__ W2,
                                                 float* __restrict__ partials) {
  __shared__ float As[32][68];   // [kk][zrow]
  __shared__ float Ws[32][68];   // [kk][j]
  __shared__ float part[64][17];
  const int bj = blockIdx.x;     // j tile (0..7)
  const int bi = blockIdx.y;     // zr tile (0..7)
  const int tid = threadIdx.x;
  const int tx = tid & 15, ty = tid >> 4;
  const int zr0 = bi * 64, j0 = bj * 64;
  float acc[4][4] = {};

  const int zrow = tid >> 2, kz0 = (tid & 3) * 8;
  const int dd = tid >> 3, jj0 = (tid & 7) * 8;
  for (int kt = 0; kt < 64; ++kt) {
    float4 za = *(const float4*)(Z + (size_t)(zr0 + zrow) * DIM + kt * 32 + kz0);
    float4 zb = *(const float4*)(Z + (size_t)(zr0 + zrow) * DIM + kt * 32 + kz0 + 4);
    float4 wa = *(const float4*)(W1 + (size_t)(kt * 32 + dd) * HID + j0 + jj0);
    float4 wb = *(const float4*)(W1 + (size_t)(kt * 32 + dd) * HID + j0 + jj0 + 4);
    __syncthreads();
    As[kz0 + 0][zrow] = za.x; As[kz0 + 1][zrow] = za.y;
    As[kz0 + 2][zrow] = za.z; As[kz0 + 3][zrow] = za.w;
    As[kz0 + 4][zrow] = zb.x; As[kz0 + 5][zrow] = zb.y;
    As[kz0 + 6][zrow] = zb.z; As[kz0 + 7][zrow] = zb.w;
    *(float4*)(&Ws[dd][jj0]) = wa;
    *(float4*)(&Ws[dd][jj0 + 4]) = wb;
    __syncthreads();
    #pragma unroll
    for (int kk = 0; kk < 32; ++kk) {
      float a[4], w[4];
      *(float4*)a = *(const float4*)(&As[kk][ty * 4]);
      *(float4*)w = *(const float4*)(&Ws[kk][tx * 4]);
      #pragma unroll
      for (int i = 0; i < 4; ++i)
        #pragma unroll
        for (int j = 0; j < 4; ++j)
          acc[i][j] = fmaf(a[i], w[j], acc[i][j]);
    }
  }
  float psum[4] = {0.f, 0.f, 0.f, 0.f};
  #pragma unroll
  for (int j = 0; j < 4; ++j) {
    int jj = j0 + tx * 4 + j;
    float b = b1[jj], w2 = W2[jj];
    #pragma unroll
    for (int i = 0; i < 4; ++i) {
      float h = acc[i][j] + b;
      h = h >= 0.f ? h : 0.01f * h;
      psum[i] = fmaf(h, w2, psum[i]);
    }
  }
  #pragma unroll
  for (int i = 0; i < 4; ++i) part[ty * 4 + i][tx] = psum[i];
  __syncthreads();
  if (tid < 64) {
    float s = 0.f;
    #pragma unroll
    for (int x = 0; x < 16; ++x) s += part[tid][x];
    partials[(size_t)(zr0 + tid) * 8 + bj] = s;
  }
}

// ---------------- final: logits -> BCE loss ----------------
__global__ __launch_bounds__(512) void final_kernel(const float* __restrict__ partials,
                                                    const float* __restrict__ b2,
                                                    float* __restrict__ out) {
  __shared__ float red[512];
  int zr = threadIdx.x;
  float lg = b2[0];
  for (int bj = 0; bj < 8; ++bj) lg += partials[(size_t)zr * 8 + bj];
  float x = (zr & 1) ? lg : -lg;   // even zr = pos (softplus(-logit)), odd = neg
  float sp = fmaxf(x, 0.f) + log1pf(expf(-fabsf(x)));
  red[zr] = sp * (1.0f / 256.0f);
  __syncthreads();
  for (int st = 256; st; st >>= 1) {
    if (zr < st) red[zr] += red[zr + st];
    __syncthreads();
  }
  if (zr == 0) out[0] = red[0];
}

// ---------------- launch ----------------
extern "C" void kernel_launch(void* const* d_in, const int* in_sizes, int n_in,
                              void* d_out, int out_size, void* d_ws, size_t ws_size,
                              hipStream_t stream) {
  (void)in_sizes; (void)n_in; (void)out_size; (void)ws_size;
  const float* inputs = (const float*)d_in[0];
  const int* targets  = (const int*)d_in[1];
  const float* F      = (const float*)d_in[2];
  const int* labels   = (const int*)d_in[3];
  const float* W1     = (const float*)d_in[4];
  const float* b1     = (const float*)d_in[5];
  const float* W2     = (const float*)d_in[6];
  const float* b2     = (const float*)d_in[7];
  float* out = (float*)d_out;

  char* ws = (char*)d_ws;
  size_t off = 0;
  ushort* Abf     = (ushort*)(ws + off); off += (size_t)B_ROWS * DIM * 2;        // 1 MB
  float* cand_val = (float*)(ws + off); off += (size_t)B_ROWS * CAND_CAP * 4;    // 1 MB
  int* cand_idx   = (int*)(ws + off);   off += (size_t)B_ROWS * CAND_CAP * 4;    // 1 MB
  int* cand_cnt   = (int*)(ws + off);   off += 1024;
  unsigned long long* pos_comb = (unsigned long long*)(ws + off); off += 2048;
  float* invn     = (float*)(ws + off); off += 1024;
  float* thr      = (float*)(ws + off); off += 1024;
  float* partials = (float*)(ws + off); off += 512 * 8 * 4;                      // 16 KB
  off = (off + 255) & ~(size_t)255;
  float* Z        = (float*)(ws + off); off += (size_t)512 * DIM * 4;            // 4 MB

  zero_kernel<<<1, 256, 0, stream>>>(cand_cnt, pos_comb);
  prep_pos<<<512, 256, 0, stream>>>(inputs, Abf, invn, thr, labels, targets, pos_comb);
  gemm_select<<<N_BANK / 64, 256, 0, stream>>>(Abf, F, thr, labels, targets,
                                               cand_val, cand_idx, cand_cnt);
  tail_kernel<<<B_ROWS, 512, 0, stream>>>(inputs, F, cand_val, cand_idx, cand_cnt,
                                          pos_comb, invn, Z);
  head_gemm<<<dim3(8, 8), 256, 0, stream>>>(Z, W1, b1, W2, partials);
  final_kernel<<<1, 512, 0, stream>>>(partials, b2, out);
}

// Round 10
// 631.469 us; speedup vs baseline: 1.5986x; 1.0908x over previous
//
#include <hip/hip_runtime.h>
#include <hip/hip_bf16.h>
#include <stdint.h>

#define N_BANK 131072
#define B_ROWS 256
#define DIM 2048
#define HID 512
#define CAND_CAP 1024
#define WIN 64
#define Z_THRESH 2.5528f

typedef __attribute__((ext_vector_type(8))) short bf16x8;
typedef __attribute__((ext_vector_type(8))) unsigned short ushort8;
typedef __attribute__((ext_vector_type(4))) float f32x4;

// ---------------- threefry2x32 (exact JAX semantics; verified R1-R9) ----------------
__device__ __forceinline__ void threefry2x32(uint32_t k0, uint32_t k1,
                                             uint32_t x0, uint32_t x1,
                                             uint32_t& o0, uint32_t& o1) {
  uint32_t ks0 = k0, ks1 = k1, ks2 = k0 ^ k1 ^ 0x1BD11BDAu;
  uint32_t ks[3] = {ks0, ks1, ks2};
  x0 += ks0; x1 += ks1;
  const int rotA[4] = {13, 15, 26, 6};
  const int rotB[4] = {17, 29, 16, 24};
  #pragma unroll
  for (int g = 0; g < 5; ++g) {
    const int* rr = (g & 1) ? rotB : rotA;
    #pragma unroll
    for (int i = 0; i < 4; ++i) {
      x0 += x1;
      x1 = (x1 << rr[i]) | (x1 >> (32 - rr[i]));
      x1 ^= x0;
    }
    x0 += ks[(g + 1) % 3];
    x1 += ks[(g + 2) % 3] + (uint32_t)(g + 1);
  }
  o0 = x0; o1 = x1;
}

__device__ __forceinline__ void jax_split(uint32_t k0, uint32_t k1,
                                          uint32_t& a0, uint32_t& a1,
                                          uint32_t& b0, uint32_t& b1) {
  uint32_t o00, o10, o01, o11;
  threefry2x32(k0, k1, 0u, 2u, o00, o10);
  threefry2x32(k0, k1, 1u, 3u, o01, o11);
  a0 = o00; a1 = o01;
  b0 = o10; b1 = o11;
}

__device__ __forceinline__ ushort f2bf(float f) {
  uint32_t u = __float_as_uint(f);
  return (ushort)((u + 0x7FFFu + ((u >> 16) & 1u)) >> 16);  // RNE
}

__device__ __forceinline__ uint32_t cvt_pk(float lo, float hi) {
  uint32_t d;
  asm("v_cvt_pk_bf16_f32 %0, %1, %2" : "=v"(d) : "v"(lo), "v"(hi));
  return d;
}

__device__ __forceinline__ ushort8 cvt8u(float4 a, float4 b) {
  union { uint32_t u[4]; ushort8 v; } r;
  r.u[0] = cvt_pk(a.x, a.y);
  r.u[1] = cvt_pk(a.z, a.w);
  r.u[2] = cvt_pk(b.x, b.y);
  r.u[3] = cvt_pk(b.z, b.w);
  return r.v;
}

// ---------------- zero the atomics ----------------
__global__ void zero_kernel(int* __restrict__ cand_cnt,
                            unsigned long long* __restrict__ pos_comb) {
  int t = threadIdx.x;
  cand_cnt[t] = 0;
  pos_comb[t] = 0ull;
}

// ---------------- fused prep (rows 0-255) + pos_scan (all 512 blocks) ----------------
// Abf fragment-order layout (verified R5-R9): 16B chunk =
// kt*2048 + wid*512 + kk*256 + fi*64 + lk*16 + lr, holding row=wid*64+fi*16+lr,
// k = kt*64 + kk*32 + lk*8 .. +8.
__global__ __launch_bounds__(256) void prep_pos(const float* __restrict__ inputs,
                                                ushort* __restrict__ Abf,
                                                float* __restrict__ invn,
                                                float* __restrict__ thr,
                                                const int* __restrict__ labels,
                                                const int* __restrict__ targets,
                                                unsigned long long* __restrict__ pos_comb) {
  int bid = blockIdx.x, t = threadIdx.x;
  __shared__ int targ_s[256];
  __shared__ uint32_t bm[128];
  __shared__ double red[256];
  if (t < 128) bm[t] = 0u;
  int tg = targets[t];
  targ_s[t] = tg;

  double s = 0.0;
  if (bid < 256) {
    const float* src = inputs + (size_t)bid * DIM + t * 8;
    float4 v0 = *(const float4*)(src);
    float4 v1 = *(const float4*)(src + 4);
    s = (double)v0.x * v0.x + (double)v0.y * v0.y + (double)v0.z * v0.z + (double)v0.w * v0.w
      + (double)v1.x * v1.x + (double)v1.y * v1.y + (double)v1.z * v1.z + (double)v1.w * v1.w;
    ushort8 c = { f2bf(v0.x), f2bf(v0.y), f2bf(v0.z), f2bf(v0.w),
                  f2bf(v1.x), f2bf(v1.y), f2bf(v1.z), f2bf(v1.w) };
    int kt = t >> 3;
    int kk = (t >> 2) & 1;
    int lk = t & 3;
    int chunk = kt * 2048 + (bid >> 6) * 512 + kk * 256 + ((bid >> 4) & 3) * 64
              + lk * 16 + (bid & 15);
    *(ushort8*)(Abf + (size_t)chunk * 8) = c;
  }
  __syncthreads();
  atomicOr(&bm[tg >> 5], 1u << (tg & 31));
  __syncthreads();

  int n = bid * 256 + t;
  int c = labels[n];
  if ((bm[c >> 5] >> (c & 31)) & 1u) {
    uint32_t kn0, kn1, kp0, kp1;
    jax_split(0u, 42u, kn0, kn1, kp0, kp1);
    for (int r = 0; r < 256; ++r) {
      if (targ_s[r] == c) {
        uint32_t i = (uint32_t)r * (uint32_t)N_BANK + (uint32_t)n;
        uint32_t o0, o1, bits;
        if (i < (1u << 24)) { threefry2x32(kp0, kp1, i, i + (1u << 24), o0, o1); bits = o0; }
        else                { threefry2x32(kp0, kp1, i - (1u << 24), i, o0, o1); bits = o1; }
        unsigned long long comb =
            ((unsigned long long)((bits >> 9) + 1u) << 32) | (unsigned long long)(131071u - (uint32_t)n);
        atomicMax(&pos_comb[r], comb);
      }
    }
  }

  if (bid < 256) {
    red[t] = s;
    __syncthreads();
    for (int st = 128; st; st >>= 1) {
      if (t < st) red[t] += red[t + st];
      __syncthreads();
    }
    if (t == 0) {
      float nrm = sqrtf((float)red[0]);
      invn[bid] = 1.0f / nrm;
      thr[bid] = Z_THRESH * nrm;
    }
  }
}

// ---------------- bf16 MFMA GEMM + fused select: R5 body + pinned depth-2 F ----------------
// BM=256 (full M: F read once), BN=64, BK=64, kt = 0..31 EXACTLY.
// Per step: LOADA(kt+1) -> SB -> issue F(kt+2) regs -> SB -> MFMA(kt) ->
// cvt F(kt+1) -> bf16 ds_write -> "lgkmcnt(0); s_barrier".
// FIFO: A issued BEFORE F each step, so the MFMA's A-wait next step drains
// only A; F stays in flight ~1.8 steps (>= HBM latency). The cvt's operand
// wait is a counted vmcnt(12) (compiler), leaving A(kt+1)+F(kt+2) in flight —
// vmcnt never drains to 0 inside the loop.
#define LOADA(KT, DST)                                                        \
  {                                                                           \
    const ushort* ab = aptr + (size_t)(KT) * 16384;                           \
    _Pragma("unroll")                                                         \
    for (int q = 0; q < 8; ++q) DST[q] = *(const bf16x8*)(ab + q * 512);      \
  }

#define GMFMA(CUR, AC)                                                        \
  {                                                                           \
    _Pragma("unroll")                                                         \
    for (int kk = 0; kk < 2; ++kk) {                                          \
      bf16x8 bfv[4];                                                          \
      _Pragma("unroll")                                                       \
      for (int fj = 0; fj < 4; ++fj)                                          \
        bfv[fj] = *(const bf16x8*)(&Bs[CUR][(fj * 16 + lr) * 64 +             \
                        (((kk * 4 + lk) ^ (lr & 7)) * 8)]);                   \
      _Pragma("unroll")                                                       \
      for (int fi = 0; fi < 4; ++fi)                                          \
        _Pragma("unroll")                                                     \
        for (int fj = 0; fj < 4; ++fj)                                        \
          acc[fi][fj] = __builtin_amdgcn_mfma_f32_16x16x32_bf16(              \
              AC[kk * 4 + fi], bfv[fj], acc[fi][fj], 0, 0, 0);                \
    }                                                                         \
  }

#define SB() __builtin_amdgcn_sched_barrier(0)

#define GSTEP(KT, AC, AN, FISS, FCVT, CUR, NXT, DOA, DOF)                     \
  {                                                                           \
    if (DOA) { LOADA((KT) + 1, AN); }                                         \
    SB();                                                                     \
    if (DOF) {                                                                \
      const float* fp2 = fptr + ((KT) + 2) * 64;                              \
      FISS[0] = *(const float4*)(fp2);                                        \
      FISS[1] = *(const float4*)(fp2 + 4);                                    \
      FISS[2] = *(const float4*)(fp2 + 8);                                    \
      FISS[3] = *(const float4*)(fp2 + 12);                                   \
    }                                                                         \
    SB();                                                                     \
    GMFMA(CUR, AC);                                                           \
    if ((KT) < 31) {                                                          \
      *(ushort8*)(&Bs[NXT][bo0]) = cvt8u(FCVT[0], FCVT[1]);                   \
      *(ushort8*)(&Bs[NXT][bo1]) = cvt8u(FCVT[2], FCVT[3]);                   \
      asm volatile("s_waitcnt lgkmcnt(0)\n\ts_barrier" ::: "memory");         \
    }                                                                         \
  }

__global__ __launch_bounds__(256, 2) void gemm_select(
    const ushort* __restrict__ Abf, const float* __restrict__ F,
    const float* __restrict__ thr, const int* __restrict__ labels,
    const int* __restrict__ targets, float* __restrict__ cand_val,
    int* __restrict__ cand_idx, int* __restrict__ cand_cnt) {
  __shared__ ushort Bs[2][64 * 64];    // 16KB: [row][chunk^(row&7)] bf16
  const int tid = threadIdx.x;
  const int bn = blockIdx.x * 64;
  const int wid = tid >> 6;
  const int lane = tid & 63;
  const int lr = lane & 15;
  const int lk = lane >> 4;

  const int frow = tid >> 2;
  const int fq = tid & 3;
  const float* fptr = F + (size_t)(bn + frow) * DIM + fq * 16;
  const int fr7 = frow & 7;
  const int bo0 = frow * 64 + ((fq * 2) ^ fr7) * 8;
  const int bo1 = frow * 64 + ((fq * 2 + 1) ^ fr7) * 8;

  const ushort* aptr = Abf + (size_t)(wid * 512 + lane) * 8;

  f32x4 acc[4][4];
  #pragma unroll
  for (int i = 0; i < 4; ++i)
    #pragma unroll
    for (int j = 0; j < 4; ++j) acc[i][j] = (f32x4){0.f, 0.f, 0.f, 0.f};

  bf16x8 A0[8], A1[8];
  float4 fE[4], fO[4];

  // prologue: A(0), F(0)->fE, F(1)->fO; cvt F0 -> Bs[0]; publish
  LOADA(0, A0);
  SB();
  fE[0] = *(const float4*)(fptr);
  fE[1] = *(const float4*)(fptr + 4);
  fE[2] = *(const float4*)(fptr + 8);
  fE[3] = *(const float4*)(fptr + 12);
  fO[0] = *(const float4*)(fptr + 64);
  fO[1] = *(const float4*)(fptr + 68);
  fO[2] = *(const float4*)(fptr + 72);
  fO[3] = *(const float4*)(fptr + 76);
  SB();
  *(ushort8*)(&Bs[0][bo0]) = cvt8u(fE[0], fE[1]);
  *(ushort8*)(&Bs[0][bo1]) = cvt8u(fE[2], fE[3]);
  asm volatile("s_waitcnt lgkmcnt(0)\n\ts_barrier" ::: "memory");

  #pragma unroll 1
  for (int k2 = 0; k2 < 14; ++k2) {   // steps kt = 0..27
    int kt = 2 * k2;
    GSTEP(kt,       A0, A1, fE, fO, 0, 1, 1, 1);  // even: issue F(kt+2)->fE, cvt fO=F(kt+1)
    GSTEP((kt + 1), A1, A0, fO, fE, 1, 0, 1, 1);  // odd:  issue ->fO, cvt fE
  }
  GSTEP(28, A0, A1, fE, fO, 0, 1, 1, 1);  // F30->fE; LOADA29; cvt fO(F29)
  GSTEP(29, A1, A0, fO, fE, 1, 0, 1, 1);  // F31->fO; LOADA30; cvt fE(F30)
  GSTEP(30, A0, A1, fE, fO, 0, 1, 1, 0);  // LOADA31; cvt fO(F31)
  GSTEP(31, A1, A0, fO, fE, 1, 0, 0, 0);  // final MFMA

  // fused threshold selection (S never hits memory)
  int lb[4];
  #pragma unroll
  for (int fj = 0; fj < 4; ++fj) lb[fj] = labels[bn + fj * 16 + lr];
  #pragma unroll
  for (int fi = 0; fi < 4; ++fi) {
    #pragma unroll
    for (int reg = 0; reg < 4; ++reg) {
      int row = wid * 64 + fi * 16 + lk * 4 + reg;  // C/D: col=lane&15, row=(lane>>4)*4+reg
      float tr = thr[row];
      int tg = targets[row];
      #pragma unroll
      for (int fj = 0; fj < 4; ++fj) {
        float v = acc[fi][fj][reg];
        if (v > tr && lb[fj] != tg) {
          int p = atomicAdd(&cand_cnt[row], 1);
          if (p < CAND_CAP) {
            cand_val[row * CAND_CAP + p] = v;
            cand_idx[row * CAND_CAP + p] = bn + fj * 16 + lr;
          }
        }
      }
    }
  }
}

// ---------------- tail: windowed fp64 rerank + Z-matrix write (verified R9) ----------------
__global__ __launch_bounds__(512) void tail_kernel(const float* __restrict__ inputs,
                                                   const float* __restrict__ F,
                                                   const float* __restrict__ cand_val,
                                                   const int* __restrict__ cand_idx,
                                                   const int* __restrict__ cand_cnt,
                                                   const unsigned long long* __restrict__ pos_comb,
                                                   const float* __restrict__ invn,
                                                   float* __restrict__ Z) {
  int r = blockIdx.x;
  int tid = threadIdx.x;
  int m = cand_cnt[r]; if (m > CAND_CAP) m = CAND_CAP;
  __shared__ float vals[CAND_CAP];
  __shared__ int idxs[CAND_CAP];
  __shared__ float xr[DIM];
  __shared__ int wlist[WIN];
  __shared__ double dvals[WIN];
  __shared__ int wcnt, s_pick, s_neg;

  if (tid == 0) {
    wcnt = 0; s_neg = 0;
    uint32_t kn0, kn1, kp0, kp1, k10, k11, k20, k21, o0, o1, hi, lo;
    jax_split(0u, 42u, kn0, kn1, kp0, kp1);
    jax_split(kn0, kn1, k10, k11, k20, k21);
    if (r < 128) { threefry2x32(k10, k11, (uint32_t)r, (uint32_t)(r + 128), o0, o1); hi = o0; }
    else         { threefry2x32(k10, k11, (uint32_t)(r - 128), (uint32_t)r, o0, o1); hi = o1; }
    if (r < 128) { threefry2x32(k20, k21, (uint32_t)r, (uint32_t)(r + 128), o0, o1); lo = o0; }
    else         { threefry2x32(k20, k21, (uint32_t)(r - 128), (uint32_t)r, o0, o1); lo = o1; }
    s_pick = (int)(((hi % 500u) * 296u + (lo % 500u)) % 500u);
  }
  for (int d = tid; d < DIM; d += 512) xr[d] = inputs[(size_t)r * DIM + d];
  for (int c = tid; c < m; c += 512) {
    vals[c] = cand_val[r * CAND_CAP + c];
    idxs[c] = cand_idx[r * CAND_CAP + c];
  }
  __syncthreads();
  int pick = s_pick;
  int lo = pick - 32; if (lo < 0) lo = 0;
  int hi = pick + 32; if (hi > m) hi = m;
  for (int c = tid; c < m; c += 512) {
    float v = vals[c]; int id = idxs[c]; int rk = 0;
    for (int j = 0; j < m; ++j) {
      float vj = vals[j];
      rk += (vj > v) || (vj == v && idxs[j] < id);
    }
    if (rk >= lo && rk < hi) { int p = atomicAdd(&wcnt, 1); if (p < WIN) wlist[p] = c; }
  }
  __syncthreads();
  int wn = wcnt; if (wn > WIN) wn = WIN;
  int wave = tid >> 6, lane = tid & 63;
  for (int w = wave; w < wn; w += 8) {
    const float* f = F + (size_t)idxs[wlist[w]] * DIM;
    double s = 0.0;
    for (int d = lane; d < DIM; d += 64) s += (double)xr[d] * (double)f[d];
    for (int off = 32; off; off >>= 1) s += __shfl_down(s, off);
    if (lane == 0) dvals[w] = s;
  }
  __syncthreads();
  if (tid < wn) {
    double v = dvals[tid]; int id = idxs[wlist[tid]]; int rk = lo;
    for (int j = 0; j < wn; ++j) {
      double vj = dvals[j];
      rk += (vj > v) || (vj == v && idxs[wlist[j]] < id);
    }
    if (rk == pick) s_neg = id;
  }
  __syncthreads();

  unsigned long long pc = pos_comb[r];
  int sp = pc ? (int)(131071u - (uint32_t)(pc & 0xffffffffull)) : 0;
  int sn = s_neg;
  float inv = invn[r];
  const float* fp = F + (size_t)sp * DIM;
  const float* fn = F + (size_t)sn * DIM;
  float* zp = Z + (size_t)(2 * r) * DIM;
  float* zn = Z + (size_t)(2 * r + 1) * DIM;
  for (int d = tid; d < DIM; d += 512) {
    float x = xr[d] * inv;
    zp[d] = fabsf(x - fp[d]);
    zn[d] = fabsf(x - fn[d]);
  }
}

// ---------------- head GEMM: H = Z @ W1, fused leaky+W2 partial reduce (verified R9) ----------------
__global__ __launch_bounds__(256) void head_gemm(const float* __restrict__ Z,
                                                 const float* __restrict__ W1,
                                                 const float* __restrict__ b1,
                                                 const float* __restrict__ W2,
                                                 float* __restrict__ partials) {
  __shared__ float As[32][68];
  __shared__ float Ws[32][68];
  __shared__ float part[64][17];
  const int bj = blockIdx.x;
  const int bi = blockIdx.y;
  const int tid = threadIdx.x;
  const int tx = tid & 15, ty = tid >> 4;
  const int zr0 = bi * 64, j0 = bj * 64;
  float acc[4][4] = {};

  const int zrow = tid >> 2, kz0 = (tid & 3) * 8;
  const int dd = tid >> 3, jj0 = (tid & 7) * 8;
  for (int kt = 0; kt < 64; ++kt) {
    float4 za = *(const float4*)(Z + (size_t)(zr0 + zrow) * DIM + kt * 32 + kz0);
    float4 zb = *(const float4*)(Z + (size_t)(zr0 + zrow) * DIM + kt * 32 + kz0 + 4);
    float4 wa = *(const float4*)(W1 + (size_t)(kt * 32 + dd) * HID + j0 + jj0);
    float4 wb = *(const float4*)(W1 + (size_t)(kt * 32 + dd) * HID + j0 + jj0 + 4);
    __syncthreads();
    As[kz0 + 0][zrow] = za.x; As[kz0 + 1][zrow] = za.y;
    As[kz0 + 2][zrow] = za.z; As[kz0 + 3][zrow] = za.w;
    As[kz0 + 4][zrow] = zb.x; As[kz0 + 5][zrow] = zb.y;
    As[kz0 + 6][zrow] = zb.z; As[kz0 + 7][zrow] = zb.w;
    *(float4*)(&Ws[dd][jj0]) = wa;
    *(float4*)(&Ws[dd][jj0 + 4]) = wb;
    __syncthreads();
    #pragma unroll
    for (int kk = 0; kk < 32; ++kk) {
      float a[4], w[4];
      *(float4*)a = *(const float4*)(&As[kk][ty * 4]);
      *(float4*)w = *(const float4*)(&Ws[kk][tx * 4]);
      #pragma unroll
      for (int i = 0; i < 4; ++i)
        #pragma unroll
        for (int j = 0; j < 4; ++j)
          acc[i][j] = fmaf(a[i], w[j], acc[i][j]);
    }
  }
  float psum[4] = {0.f, 0.f, 0.f, 0.f};
  #pragma unroll
  for (int j = 0; j < 4; ++j) {
    int jj = j0 + tx * 4 + j;
    float b = b1[jj], w2 = W2[jj];
    #pragma unroll
    for (int i = 0; i < 4; ++i) {
      float h = acc[i][j] + b;
      h = h >= 0.f ? h : 0.01f * h;
      psum[i] = fmaf(h, w2, psum[i]);
    }
  }
  #pragma unroll
  for (int i = 0; i < 4; ++i) part[ty * 4 + i][tx] = psum[i];
  __syncthreads();
  if (tid < 64) {
    float s = 0.f;
    #pragma unroll
    for (int x = 0; x < 16; ++x) s += part[tid][x];
    partials[(size_t)(zr0 + tid) * 8 + bj] = s;
  }
}

// ---------------- final: logits -> BCE loss (verified R9) ----------------
__global__ __launch_bounds__(512) void final_kernel(const float* __restrict__ partials,
                                                    const float* __restrict__ b2,
                                                    float* __restrict__ out) {
  __shared__ float red[512];
  int zr = threadIdx.x;
  float lg = b2[0];
  for (int bj = 0; bj < 8; ++bj) lg += partials[(size_t)zr * 8 + bj];
  float x = (zr & 1) ? lg : -lg;
  float sp = fmaxf(x, 0.f) + log1pf(expf(-fabsf(x)));
  red[zr] = sp * (1.0f / 256.0f);
  __syncthreads();
  for (int st = 256; st; st >>= 1) {
    if (zr < st) red[zr] += red[zr + st];
    __syncthreads();
  }
  if (zr == 0) out[0] = red[0];
}

// ---------------- launch ----------------
extern "C" void kernel_launch(void* const* d_in, const int* in_sizes, int n_in,
                              void* d_out, int out_size, void* d_ws, size_t ws_size,
                              hipStream_t stream) {
  (void)in_sizes; (void)n_in; (void)out_size; (void)ws_size;
  const float* inputs = (const float*)d_in[0];
  const int* targets  = (const int*)d_in[1];
  const float* F      = (const float*)d_in[2];
  const int* labels   = (const int*)d_in[3];
  const float* W1     = (const float*)d_in[4];
  const float* b1     = (const float*)d_in[5];
  const float* W2     = (const float*)d_in[6];
  const float* b2     = (const float*)d_in[7];
  float* out = (float*)d_out;

  char* ws = (char*)d_ws;
  size_t off = 0;
  ushort* Abf     = (ushort*)(ws + off); off += (size_t)B_ROWS * DIM * 2;        // 1 MB
  float* cand_val = (float*)(ws + off); off += (size_t)B_ROWS * CAND_CAP * 4;    // 1 MB
  int* cand_idx   = (int*)(ws + off);   off += (size_t)B_ROWS * CAND_CAP * 4;    // 1 MB
  int* cand_cnt   = (int*)(ws + off);   off += 1024;
  unsigned long long* pos_comb = (unsigned long long*)(ws + off); off += 2048;
  float* invn     = (float*)(ws + off); off += 1024;
  float* thr      = (float*)(ws + off); off += 1024;
  float* partials = (float*)(ws + off); off += 512 * 8 * 4;                      // 16 KB
  off = (off + 255) & ~(size_t)255;
  float* Z        = (float*)(ws + off); off += (size_t)512 * DIM * 4;            // 4 MB

  zero_kernel<<<1, 256, 0, stream>>>(cand_cnt, pos_comb);
  prep_pos<<<512, 256, 0, stream>>>(inputs, Abf, invn, thr, labels, targets, pos_comb);
  gemm_select<<<N_BANK / 64, 256, 0, stream>>>(Abf, F, thr, labels, targets,
                                               cand_val, cand_idx, cand_cnt);
  tail_kernel<<<B_ROWS, 512, 0, stream>>>(inputs, F, cand_val, cand_idx, cand_cnt,
                                          pos_comb, invn, Z);
  head_gemm<<<dim3(8, 8), 256, 0, stream>>>(Z, W1, b1, W2, partials);
  final_kernel<<<1, 512, 0, stream>>>(partials, b2, out);
}